// Round 7
// baseline (539.118 us; speedup 1.0000x reference)
//
#include <hip/hip_runtime.h>

#define D 360
#define NAG 64
#define NB 60
#define NPAN 6
#define FTH 540                       // 36*15 threads; 10 items each; q const/thread
#define COV_OFF (NAG * D)
#define INIT_OFF (COV_OFF + NAG * D * D)
// ping-pong R stash in d_ws: [parity][agent][ct][60][60]
#define RBOFF(par, ag, ct) ((((par) * NAG + (ag)) * 6 + (ct)) * 3600)

__device__ __forceinline__ int gshift(int i) {
    return ((i % 60) < 58) ? (i + 2) : i;
}

// ------- build: S (upd) / final cov (others) + mean/flag + R0 stash ---------
__global__ __launch_bounds__(384) void build_kernel(
    const float* __restrict__ P, const float* __restrict__ mean_in,
    const float* __restrict__ obs, const float* __restrict__ rs,
    const int* __restrict__ init_f, const int* __restrict__ sel_f,
    float* __restrict__ out, float* __restrict__ rb)
{
    const int by = blockIdx.x, ag = blockIdx.y, t = threadIdx.x;
    const bool ini = init_f[ag] != 0, sel = sel_f[ag] != 0;
    const float c = rs[ag] + 1.0f;
    if (by == 45) {   // fused "small" block: mean passthrough/init + flag
        if (t < D) {
            float v = (sel && !ini) ? obs[ag * D + t] : mean_in[ag * D + t];
            out[ag * D + t] = v;     // upd agents overwritten by solve_mean
        }
        if (t == 0) out[INIT_OFF + ag] = (ini || sel) ? 1.0f : 0.0f;
        return;
    }
    if (t >= D) return;
    const float* Pa = P + (size_t)ag * D * D;
    float* cov = out + COV_OFF + (size_t)ag * D * D;
    const int j = t;
    if (sel && ini) {
        const int gj = gshift(j);
        #pragma unroll
        for (int s = 0; s < 8; ++s) {
            const int i = by * 8 + s;
            float v = Pa[(size_t)gshift(i) * D + gj];
            if (i == j) v += 1.0f + c;           // + process(1) + obs(c)
            cov[(size_t)i * D + j] = v;
            if (i < NB && j >= NB)               // stash R slices for pass 0
                rb[RBOFF(0, ag, j / NB) + i * NB + (j % NB)] = v;
        }
    } else if (sel) {
        #pragma unroll
        for (int s = 0; s < 8; ++s) {
            const int i = by * 8 + s;
            cov[(size_t)i * D + j] = Pa[(size_t)i * D + j] + ((i == j) ? c : 0.0f);
        }
    } else {
        #pragma unroll
        for (int s = 0; s < 8; ++s) {
            const int i = by * 8 + s;
            cov[(size_t)i * D + j] = Pa[(size_t)i * D + j];
        }
    }
}

// ---------------- 4x4 in-place GJ inverse (no pivoting; SPD blocks) ----------
__device__ __forceinline__ void inv4(float4& m0, float4& m1, float4& m2, float4& m3)
{
    float pv, f;
    pv = 1.0f / m0.x;
    m0.y *= pv; m0.z *= pv; m0.w *= pv; m0.x = pv;
    f = m1.x; m1.y = fmaf(-f, m0.y, m1.y); m1.z = fmaf(-f, m0.z, m1.z); m1.w = fmaf(-f, m0.w, m1.w); m1.x = -f * pv;
    f = m2.x; m2.y = fmaf(-f, m0.y, m2.y); m2.z = fmaf(-f, m0.z, m2.z); m2.w = fmaf(-f, m0.w, m2.w); m2.x = -f * pv;
    f = m3.x; m3.y = fmaf(-f, m0.y, m3.y); m3.z = fmaf(-f, m0.z, m3.z); m3.w = fmaf(-f, m0.w, m3.w); m3.x = -f * pv;
    pv = 1.0f / m1.y;
    m1.x *= pv; m1.z *= pv; m1.w *= pv; m1.y = pv;
    f = m0.y; m0.x = fmaf(-f, m1.x, m0.x); m0.z = fmaf(-f, m1.z, m0.z); m0.w = fmaf(-f, m1.w, m0.w); m0.y = -f * pv;
    f = m2.y; m2.x = fmaf(-f, m1.x, m2.x); m2.z = fmaf(-f, m1.z, m2.z); m2.w = fmaf(-f, m1.w, m2.w); m2.y = -f * pv;
    f = m3.y; m3.x = fmaf(-f, m1.x, m3.x); m3.z = fmaf(-f, m1.z, m3.z); m3.w = fmaf(-f, m1.w, m3.w); m3.y = -f * pv;
    pv = 1.0f / m2.z;
    m2.x *= pv; m2.y *= pv; m2.w *= pv; m2.z = pv;
    f = m0.z; m0.x = fmaf(-f, m2.x, m0.x); m0.y = fmaf(-f, m2.y, m0.y); m0.w = fmaf(-f, m2.w, m0.w); m0.z = -f * pv;
    f = m1.z; m1.x = fmaf(-f, m2.x, m1.x); m1.y = fmaf(-f, m2.y, m1.y); m1.w = fmaf(-f, m2.w, m1.w); m1.z = -f * pv;
    f = m3.z; m3.x = fmaf(-f, m2.x, m3.x); m3.y = fmaf(-f, m2.y, m3.y); m3.w = fmaf(-f, m2.w, m3.w); m3.z = -f * pv;
    pv = 1.0f / m3.w;
    m3.x *= pv; m3.y *= pv; m3.z *= pv; m3.w = pv;
    f = m0.w; m0.x = fmaf(-f, m3.x, m0.x); m0.y = fmaf(-f, m3.y, m0.y); m0.z = fmaf(-f, m3.z, m0.z); m0.w = -f * pv;
    f = m1.w; m1.x = fmaf(-f, m3.x, m1.x); m1.y = fmaf(-f, m3.y, m1.y); m1.z = fmaf(-f, m3.z, m1.z); m1.w = -f * pv;
    f = m2.w; m2.x = fmaf(-f, m3.x, m2.x); m2.y = fmaf(-f, m3.y, m2.y); m2.z = fmaf(-f, m3.z, m2.z); m2.w = -f * pv;
}

// ------ factor: block-pivot (mb=4) GJ with the panel slab resident in LDS ----
// Hazard-free single barrier/step: pivot rows come from praw[] (staged during
// the PREVIOUS step by their owners), pivot-column values from fcol[] (same).
// Every slab cell is read only by its owning thread within a step.
__global__ __launch_bounds__(FTH) void factor_kernel(
    float* __restrict__ out, const float* __restrict__ rs,
    const int* __restrict__ init_f, const int* __restrict__ sel_f,
    float* __restrict__ rb, int p)
{
    const int ag = blockIdx.x;
    if (!(init_f[ag] && sel_f[ag])) return;
    float* M = out + COV_OFF + (size_t)ag * D * D;
    const int j0 = p * NB;
    const int t = threadIdx.x;
    __shared__ float  slab[D][NB];       // 86.4 KB
    __shared__ float4 praw[2][4][15];    // raw pivot rows (dbuf)       1.9 KB
    __shared__ float4 fcol[2][D];        // next pivot-col block (dbuf) 11.5 KB
    const int q  = t % 15;               // FTH = 36*15 -> q constant per thread
    const int r0 = t / 15;               // r = r0 + 36k
    // load slab (coalesced 16B per lane, 10 items/thread)
    #pragma unroll
    for (int k = 0; k < 10; ++k) {
        const int r = r0 + 36 * k;
        *(float4*)&slab[r][4 * q] = *(const float4*)(M + (size_t)r * D + j0 + 4 * q);
    }
    __syncthreads();
    if (t < 60) praw[0][t / 15][t % 15] = *(float4*)&slab[j0 + t / 15][4 * (t % 15)];
    if (t < D)  fcol[0][t] = *(float4*)&slab[t][0];
    __syncthreads();

    for (int kb = 0; kb < 15; ++kb) {
        const int buf = kb & 1;
        float4 m0 = praw[buf][0][kb], m1 = praw[buf][1][kb],
               m2 = praw[buf][2][kb], m3 = praw[buf][3][kb];
        inv4(m0, m1, m2, m3);
        const int pr0 = j0 + 4 * kb;
        #pragma unroll
        for (int k = 0; k < 10; ++k) {
            const int r = r0 + 36 * k;
            const int ii = r - pr0;
            const bool ispiv = (ii >= 0) && (ii < 4);
            float4 sc;
            if (ispiv) {
                sc = (ii == 0) ? m0 : (ii == 1) ? m1 : (ii == 2) ? m2 : m3;  // Binv row
            } else {
                const float4 fr = fcol[buf][r];
                sc.x = -(fr.x * m0.x + fr.y * m1.x + fr.z * m2.x + fr.w * m3.x);
                sc.y = -(fr.x * m0.y + fr.y * m1.y + fr.z * m2.y + fr.w * m3.y);
                sc.z = -(fr.x * m0.z + fr.y * m1.z + fr.z * m2.z + fr.w * m3.z);
                sc.w = -(fr.x * m0.w + fr.y * m1.w + fr.z * m2.w + fr.w * m3.w);
            }
            float4 v;
            if (q == kb) {
                v = sc;
            } else {
                const float4 p0 = praw[buf][0][q], p1 = praw[buf][1][q],
                             p2 = praw[buf][2][q], p3 = praw[buf][3][q];
                float4 b;
                if (ispiv) b = make_float4(0.f, 0.f, 0.f, 0.f);
                else       b = *(float4*)&slab[r][4 * q];
                v.x = fmaf(sc.x, p0.x, fmaf(sc.y, p1.x, fmaf(sc.z, p2.x, fmaf(sc.w, p3.x, b.x))));
                v.y = fmaf(sc.x, p0.y, fmaf(sc.y, p1.y, fmaf(sc.z, p2.y, fmaf(sc.w, p3.y, b.y))));
                v.z = fmaf(sc.x, p0.z, fmaf(sc.y, p1.z, fmaf(sc.z, p2.z, fmaf(sc.w, p3.z, b.z))));
                v.w = fmaf(sc.x, p0.w, fmaf(sc.y, p1.w, fmaf(sc.z, p2.w, fmaf(sc.w, p3.w, b.w))));
            }
            *(float4*)&slab[r][4 * q] = v;
            if (kb < 14) {
                if (q == kb + 1) fcol[buf ^ 1][r] = v;          // next fr column
                const int ni = r - (pr0 + 4);
                if (ni >= 0 && ni < 4) praw[buf ^ 1][ni][q] = v; // next pivot rows
            }
        }
        __syncthreads();
    }

    // writeback (+ last-pass transform, + R stash for next pass's ct==p)
    const float c = rs[ag] + 1.0f;
    const float c2 = c * c;
    #pragma unroll
    for (int k = 0; k < 10; ++k) {
        const int r = r0 + 36 * k;
        const float4 v = *(float4*)&slab[r][4 * q];
        float* dst = M + (size_t)r * D + j0 + 4 * q;
        if (p == NPAN - 1) {
            const int cg = j0 + 4 * q;
            float4 o;
            o.x = ((r == cg + 0) ? c : 0.f) - c2 * v.x;
            o.y = ((r == cg + 1) ? c : 0.f) - c2 * v.y;
            o.z = ((r == cg + 2) ? c : 0.f) - c2 * v.z;
            o.w = ((r == cg + 3) ? c : 0.f) - c2 * v.w;
            *(float4*)dst = o;
        } else {
            *(float4*)dst = v;
            const int nrel = r - NB * (p + 1);
            if (nrel >= 0 && nrel < NB)
                *(float4*)(rb + RBOFF((p + 1) & 1, ag, p) + nrel * NB + 4 * q) = v;
        }
    }
}

// -------- update: M[:,ct] = (rt==p?0:M) + F*R ; R from stash; stash next R ---
__device__ __forceinline__ void mm_row(const float4 a, const float4 b0, const float4 b1,
                                       const float4 b2, const float4 b3, float acc[4]) {
    acc[0] = fmaf(a.x, b0.x, fmaf(a.y, b1.x, fmaf(a.z, b2.x, fmaf(a.w, b3.x, acc[0]))));
    acc[1] = fmaf(a.x, b0.y, fmaf(a.y, b1.y, fmaf(a.z, b2.y, fmaf(a.w, b3.y, acc[1]))));
    acc[2] = fmaf(a.x, b0.z, fmaf(a.y, b1.z, fmaf(a.z, b2.z, fmaf(a.w, b3.z, acc[2]))));
    acc[3] = fmaf(a.x, b0.w, fmaf(a.y, b1.w, fmaf(a.z, b2.w, fmaf(a.w, b3.w, acc[3]))));
}

__global__ __launch_bounds__(256) void update_kernel(
    float* __restrict__ out, const float* __restrict__ rs,
    const int* __restrict__ init_f, const int* __restrict__ sel_f,
    float* __restrict__ rb, int p)
{
    const int ag = blockIdx.x;
    if (!(init_f[ag] && sel_f[ag])) return;
    const int ct = blockIdx.y + (blockIdx.y >= p ? 1 : 0);
    float* M = out + COV_OFF + (size_t)ag * D * D;
    const int j0 = p * NB, c0 = ct * NB;
    const float c = rs[ag] + 1.0f;
    const float c2 = c * c;
    __shared__ float R[NB][NB + 8];
    __shared__ float F[NB][NB + 8];
    const int t = threadIdx.x;
    {   // R from the race-free stash
        const float* rsrc = rb + RBOFF(p & 1, ag, ct);
        for (int idx = t; idx < NB * 15; idx += 256) {
            int k = idx / 15, qq = idx % 15;
            *(float4*)&R[k][4 * qq] = *(const float4*)(rsrc + k * NB + 4 * qq);
        }
    }
    const int tx = t % 16, ty = t / 16;
    for (int rr = 0; rr < 2; ++rr) {
        const int rt = (int)blockIdx.z * 2 + rr;
        const int r0 = rt * NB;
        __syncthreads();
        for (int idx = t; idx < NB * 15; idx += 256) {
            int rrw = idx / 15, qq = idx % 15;
            float4 v = *(const float4*)(M + (size_t)(r0 + rrw) * D + j0 + 4 * qq);
            if (p == NPAN - 1) {
                // factor wrote transformed panel: recover raw F
                const int rg = r0 + rrw, cg = j0 + 4 * qq;
                v.x = (((rg == cg + 0) ? c : 0.f) - v.x) / c2;
                v.y = (((rg == cg + 1) ? c : 0.f) - v.y) / c2;
                v.z = (((rg == cg + 2) ? c : 0.f) - v.z) / c2;
                v.w = (((rg == cg + 3) ? c : 0.f) - v.w) / c2;
            }
            *(float4*)&F[rrw][4 * qq] = v;
        }
        __syncthreads();
        if (tx < 15 && ty < 15) {
            float acc[4][4];
            #pragma unroll
            for (int i = 0; i < 4; ++i)
                #pragma unroll
                for (int j = 0; j < 4; ++j) acc[i][j] = 0.0f;
            for (int kq = 0; kq < 15; ++kq) {
                float4 a0 = *(const float4*)&F[4 * ty + 0][4 * kq];
                float4 a1 = *(const float4*)&F[4 * ty + 1][4 * kq];
                float4 a2 = *(const float4*)&F[4 * ty + 2][4 * kq];
                float4 a3 = *(const float4*)&F[4 * ty + 3][4 * kq];
                float4 b0 = *(const float4*)&R[4 * kq + 0][4 * tx];
                float4 b1 = *(const float4*)&R[4 * kq + 1][4 * tx];
                float4 b2 = *(const float4*)&R[4 * kq + 2][4 * tx];
                float4 b3 = *(const float4*)&R[4 * kq + 3][4 * tx];
                mm_row(a0, b0, b1, b2, b3, acc[0]);
                mm_row(a1, b0, b1, b2, b3, acc[1]);
                mm_row(a2, b0, b1, b2, b3, acc[2]);
                mm_row(a3, b0, b1, b2, b3, acc[3]);
            }
            #pragma unroll
            for (int i = 0; i < 4; ++i) {
                const int rg = r0 + 4 * ty + i;
                float* dst = M + (size_t)rg * D + c0 + 4 * tx;
                float4 base;
                if (rt == p) { base = make_float4(0.f, 0.f, 0.f, 0.f); }
                else         { base = *(const float4*)dst; }
                float4 v;
                v.x = base.x + acc[i][0];
                v.y = base.y + acc[i][1];
                v.z = base.z + acc[i][2];
                v.w = base.w + acc[i][3];
                if (p < NPAN - 1) {
                    // stash next pass's R slice (rows of next panel, this col-tile)
                    if (rt == p + 1 && ct != p + 1) {
                        float* rdst = rb + RBOFF((p + 1) & 1, ag, ct) + (4 * ty + i) * NB + 4 * tx;
                        *(float4*)rdst = v;
                    }
                    *(float4*)dst = v;
                } else {
                    // last pass: fold finalize  cov = c*I - c^2 * Sinv
                    const int cg = c0 + 4 * tx;
                    float4 o;
                    o.x = ((rg == cg + 0) ? c : 0.f) - c2 * v.x;
                    o.y = ((rg == cg + 1) ? c : 0.f) - c2 * v.y;
                    o.z = ((rg == cg + 2) ? c : 0.f) - c2 * v.z;
                    o.w = ((rg == cg + 3) ? c : 0.f) - c2 * v.w;
                    *(float4*)dst = o;
                }
            }
        }
    }
}

// ------- mean: m = obs - c*Sinv*d, via transformed C:  m = obs - d + (C^T d)/c
__global__ __launch_bounds__(384) void solve_mean_kernel(
    float* __restrict__ out, const float* __restrict__ mean_in,
    const float* __restrict__ obs, const float* __restrict__ rs,
    const int* __restrict__ init_f, const int* __restrict__ sel_f)
{
    const int ag = blockIdx.x;
    if (!(init_f[ag] && sel_f[ag])) return;
    const float* C = out + COV_OFF + (size_t)ag * D * D;
    __shared__ float dsh[D];
    const int t = threadIdx.x;
    if (t < D) dsh[t] = obs[ag * D + t] - mean_in[ag * D + gshift(t)];
    __syncthreads();
    if (t < D) {
        float dot = 0.0f;
        #pragma unroll 8
        for (int j = 0; j < D; ++j)
            dot = fmaf(C[(size_t)j * D + t], dsh[j], dot);   // coalesced col read
        const float c = rs[ag] + 1.0f;
        out[ag * D + t] = obs[ag * D + t] - dsh[t] + dot / c;
    }
}

extern "C" void kernel_launch(void* const* d_in, const int* in_sizes, int n_in,
                              void* d_out, int out_size, void* d_ws, size_t ws_size,
                              hipStream_t stream) {
    const float* mean_in     = (const float*)d_in[0];
    const float* P           = (const float*)d_in[1];
    const float* obs         = (const float*)d_in[2];
    const float* rs          = (const float*)d_in[3];
    const int*   initialized = (const int*)d_in[4];
    const int*   selected    = (const int*)d_in[5];
    float* out = (float*)d_out;
    float* rb  = (float*)d_ws;   // 2*64*6*3600 floats = 11.1 MB

    build_kernel<<<dim3(46, NAG), 384, 0, stream>>>(P, mean_in, obs, rs,
                                                    initialized, selected, out, rb);
    for (int p = 0; p < NPAN; ++p) {
        factor_kernel<<<NAG, FTH, 0, stream>>>(out, rs, initialized, selected, rb, p);
        update_kernel<<<dim3(NAG, NPAN - 1, 3), 256, 0, stream>>>(out, rs, initialized,
                                                                  selected, rb, p);
    }
    solve_mean_kernel<<<NAG, 384, 0, stream>>>(out, mean_in, obs, rs, initialized, selected);
}